// Round 5
// baseline (1444.269 us; speedup 1.0000x reference)
//
#include <hip/hip_runtime.h>
#include <stdint.h>
#include <math.h>

#define DM   128
#define NH   8
#define EHD  16
#define NLAY 5
#define DFF  64
#define NREP 128
#define NB   8
#define SL   4096
#define NC   27
#define NBH  (NB*NH)      // 64
#define NROWS (NB*SL)     // 32768

typedef _Float16 f16;
typedef f16 f16x8 __attribute__((ext_vector_type(8)));
typedef float f32x16 __attribute__((ext_vector_type(16)));

// ---------------- threefry2x32 (JAX-exact) ----------------
__device__ __forceinline__ uint32_t rotl32(uint32_t v, int d) {
  return (v << d) | (v >> (32 - d));
}

__device__ __forceinline__ void tf2x32(uint32_t k0, uint32_t k1,
                                       uint32_t x0, uint32_t x1,
                                       uint32_t &o0, uint32_t &o1) {
  uint32_t ks2 = k0 ^ k1 ^ 0x1BD11BDAu;
  x0 += k0; x1 += k1;
#define TFR(r) { x0 += x1; x1 = rotl32(x1, (r)); x1 ^= x0; }
  TFR(13) TFR(15) TFR(26) TFR(6)
  x0 += k1; x1 += ks2 + 1u;
  TFR(17) TFR(29) TFR(16) TFR(24)
  x0 += ks2; x1 += k0 + 2u;
  TFR(13) TFR(15) TFR(26) TFR(6)
  x0 += k0; x1 += k1 + 3u;
  TFR(17) TFR(29) TFR(16) TFR(24)
  x0 += k1; x1 += ks2 + 4u;
  TFR(13) TFR(15) TFR(26) TFR(6)
  x0 += ks2; x1 += k0 + 5u;
#undef TFR
  o0 = x0; o1 = x1;
}

// bitsT[u*SL + l] = counter-mode bits for flat counter i = l*NC + u (coalesced write)
__global__ void gen_bits_kernel(uint32_t* __restrict__ bitsT, int layer) {
  int j = blockIdx.x * blockDim.x + threadIdx.x;
  if (j >= SL * NC) return;
  int u = j >> 12;          // j / SL
  int l = j & (SL - 1);     // j % SL
  uint32_t i = (uint32_t)(l * NC + u);
  uint32_t ka, kb, k2a, k2b, y0, y1;
  tf2x32(0u, 42u, 0u, (uint32_t)layer, ka, kb);
  tf2x32(ka, kb, 0u, 1u, k2a, k2b);
  tf2x32(k2a, k2b, 0u, i, y0, y1);
  bitsT[j] = y0 ^ y1;
}

// ---------------- x[b,d,l] -> h[b,l,d], LDS-tiled ----------------
__global__ __launch_bounds__(256) void transpose_x_kernel(const float* __restrict__ x,
                                                          float* __restrict__ h) {
  __shared__ float t[32][33];
  int tid = threadIdx.x;
  int tx = tid & 31, ty = tid >> 5;
  int l0 = blockIdx.x * 32, d0 = blockIdx.y * 32, b = blockIdx.z;
#pragma unroll
  for (int j = 0; j < 4; ++j) {
    int d = d0 + ty + 8 * j;
    t[ty + 8 * j][tx] = x[((size_t)b * DM + d) * SL + l0 + tx];
  }
  __syncthreads();
#pragma unroll
  for (int j = 0; j < 4; ++j) {
    int l = l0 + ty + 8 * j;
    h[((size_t)b * SL + l) * DM + d0 + tx] = t[tx][ty + 8 * j];
  }
}

// ---------------- weight prep: fp32 -> f16 hi/lo, MFMA frag layout ----------------
#define PACK_TOTAL 425984
__global__ __launch_bounds__(256) void prep_weights(
    const float* __restrict__ Wq, const float* __restrict__ Wk,
    const float* __restrict__ Wv, const float* __restrict__ Wo,
    const float* __restrict__ W1, const float* __restrict__ W2,
    const float* __restrict__ Wp, f16* __restrict__ phi, f16* __restrict__ plo) {
  int idx = blockIdx.x * 256 + threadIdx.x;
  if (idx >= PACK_TOTAL) return;
  const float* src; int K, KS16, lsh; int f; bool transp = false;
  if (idx >= 409600) { f = idx - 409600; src = Wp; K = 128; KS16 = 8; lsh = 3; transp = true; }
  else {
    int layer = idx / 81920; int r = idx - layer * 81920;
    if      (r < 16384) { src = Wq + layer * 16384; f = r;         K = 128; KS16 = 8; lsh = 3; }
    else if (r < 32768) { src = Wk + layer * 16384; f = r - 16384; K = 128; KS16 = 8; lsh = 3; }
    else if (r < 49152) { src = Wv + layer * 16384; f = r - 32768; K = 128; KS16 = 8; lsh = 3; }
    else if (r < 65536) { src = Wo + layer * 16384; f = r - 49152; K = 128; KS16 = 8; lsh = 3; }
    else if (r < 73728) { src = W1 + layer * 8192;  f = r - 65536; K = 128; KS16 = 8; lsh = 3; }
    else                { src = W2 + layer * 8192;  f = r - 73728; K = 64;  KS16 = 4; lsh = 2; }
  }
  int j = f & 7, lane = (f >> 3) & 63, rest = f >> 9;
  int ks = rest & (KS16 - 1), nt = rest >> lsh;
  int n = nt * 32 + (lane & 31);
  int kk = ks * 16 + ((lane >> 5) & 1) * 8 + j;
  float x = transp ? src[(size_t)kk * 128 + n] : src[(size_t)n * K + kk];
  f16 h = (f16)x;
  phi[idx] = h;
  plo[idx] = (f16)(x - (float)h);
}

// ---------------- split-fp16 MFMA GEMM, fused epilogues ----------------
template<int NT32, int KS16, int SRC, int EPI>
__global__ __launch_bounds__(256, 2) void gemm_fused(
    const float* __restrict__ Asrc, const f16* __restrict__ phi,
    const f16* __restrict__ plo,
    const float* __restrict__ bias0, const float* __restrict__ bias1,
    const float* __restrict__ bias2,
    float* out0, float* out1, float* out2,
    const float* __restrict__ gw, const float* __restrict__ gb,
    const float* hres) {
  constexpr int NGW = NT32 / 2;
  constexpr int K = KS16 * 16;
  __shared__ f16x8 Alds[2 * 2 * KS16 * 64];
  __shared__ f16x8 Blds[NT32 * KS16 * 64];
  __shared__ float red[64 * 4];
  int tid = threadIdx.x, lane = tid & 63, wid = tid >> 6;
  int mg = wid >> 1, ng = wid & 1;
  int row0 = blockIdx.x * 64;

  // ---- stage A (hi+lo) ----
  if constexpr (SRC == 0 || SRC == 1) {
    constexpr int OCT = 64 * (K / 8);
    for (int o = tid; o < OCT; o += 256) {
      int row = o / (K / 8);
      int k0 = (o % (K / 8)) * 8;
      float4 f0, f1;
      if constexpr (SRC == 0) {
        const float* s = Asrc + (size_t)(row0 + row) * K + k0;
        f0 = *(const float4*)(s);
        f1 = *(const float4*)(s + 4);
      } else {
        int gr = row0 + row; int bb = gr >> 12, ll = gr & (SL - 1);
        int head = k0 >> 4, e0 = k0 & 15;
        const float* s = Asrc + (((size_t)(bb * NH + head) * SL + ll) * EHD + e0);
        f0 = *(const float4*)(s);
        f1 = *(const float4*)(s + 4);
      }
      f16x8 vh, vl;
      float xs[8] = {f0.x, f0.y, f0.z, f0.w, f1.x, f1.y, f1.z, f1.w};
#pragma unroll
      for (int j = 0; j < 8; ++j) {
        f16 hh = (f16)xs[j];
        vh[j] = hh;
        vl[j] = (f16)(xs[j] - (float)hh);
      }
      int al = (row & 31) | (((k0 >> 3) & 1) << 5);
      int ks = k0 >> 4, mt = row >> 5;
      Alds[((0 * 2 + mt) * KS16 + ks) * 64 + al] = vh;
      Alds[((1 * 2 + mt) * KS16 + ks) * 64 + al] = vl;
    }
  } else {  // SRC == 3 : h rows + final LayerNorm before packing
    int row = tid >> 2, q4 = tid & 3;
    const float* s = Asrc + (size_t)(row0 + row) * 128 + q4 * 32;
    float r[32];
#pragma unroll
    for (int i = 0; i < 8; ++i) {
      float4 f = *(const float4*)(s + 4 * i);
      r[4 * i] = f.x; r[4 * i + 1] = f.y; r[4 * i + 2] = f.z; r[4 * i + 3] = f.w;
    }
    float sm = 0.f, s2 = 0.f;
#pragma unroll
    for (int i = 0; i < 32; ++i) { sm += r[i]; s2 += r[i] * r[i]; }
    sm += __shfl_xor(sm, 1, 4); sm += __shfl_xor(sm, 2, 4);
    s2 += __shfl_xor(s2, 1, 4); s2 += __shfl_xor(s2, 2, 4);
    float mean = sm * (1.f / 128.f);
    float var = s2 * (1.f / 128.f) - mean * mean;
    float rstd = 1.0f / sqrtf(var + 1e-5f);
#pragma unroll
    for (int i = 0; i < 32; ++i) {
      int kk = q4 * 32 + i;
      r[i] = (r[i] - mean) * rstd * gw[kk] + gb[kk];
    }
#pragma unroll
    for (int i = 0; i < 4; ++i) {
      int k0 = q4 * 32 + i * 8;
      f16x8 vh, vl;
#pragma unroll
      for (int j = 0; j < 8; ++j) {
        float x = r[8 * i + j];
        f16 hh = (f16)x;
        vh[j] = hh;
        vl[j] = (f16)(x - (float)hh);
      }
      int al = (row & 31) | (((k0 >> 3) & 1) << 5);
      int ks = k0 >> 4, mt = row >> 5;
      Alds[((0 * 2 + mt) * KS16 + ks) * 64 + al] = vh;
      Alds[((1 * 2 + mt) * KS16 + ks) * 64 + al] = vl;
    }
  }

  constexpr int NMAT = (EPI == 0) ? 3 : 1;
  constexpr int BCNT = NT32 * KS16 * 64;  // f16x8 (=float4) count

#define STAGE_B(SRCPTR)                                        \
  {                                                            \
    const float4* bsrc = (const float4*)(SRCPTR);              \
    float4* bdst = (float4*)Blds;                              \
    _Pragma("unroll")                                          \
    for (int i = 0; i < BCNT / 256; ++i) bdst[tid + i * 256] = bsrc[tid + i * 256]; \
  }

#define GEMM_PASS(ASEL)                                                         \
  _Pragma("unroll")                                                             \
  for (int ks = 0; ks < KS16; ++ks) {                                           \
    f16x8 afr = Alds[(((ASEL) * 2 + mg) * KS16 + ks) * 64 + lane];              \
    _Pragma("unroll")                                                           \
    for (int g = 0; g < NGW; ++g) {                                             \
      f16x8 bfr = Blds[((ng * NGW + g) * KS16 + ks) * 64 + lane];               \
      acc[g] = __builtin_amdgcn_mfma_f32_32x32x16_f16(afr, bfr, acc[g], 0, 0, 0); \
    }                                                                           \
  }

  for (int m = 0; m < NMAT; ++m) {
    if (m) __syncthreads();
    STAGE_B(phi + m * 16384)
    __syncthreads();
    f32x16 acc[NGW];
#pragma unroll
    for (int g = 0; g < NGW; ++g)
#pragma unroll
      for (int j = 0; j < 16; ++j) acc[g][j] = 0.f;
    GEMM_PASS(0)
    GEMM_PASS(1)
    __syncthreads();
    STAGE_B(plo + m * 16384)
    __syncthreads();
    GEMM_PASS(0)

    // ---- epilogue ----
    int hi4 = 4 * (lane >> 5);
    if constexpr (EPI == 0) {
      const float* bm = (m == 0) ? bias0 : (m == 1) ? bias1 : bias2;
      float* om = (m == 0) ? out0 : (m == 1) ? out1 : out2;
#pragma unroll
      for (int g = 0; g < NGW; ++g) {
        int col = ng * (NGW * 32) + g * 32 + (lane & 31);
        float bv = bm[col];
        int head = col >> 4, e = col & 15;
#pragma unroll
        for (int reg = 0; reg < 16; ++reg) {
          int row_l = (reg & 3) + 8 * (reg >> 2) + hi4;
          int grow = row0 + mg * 32 + row_l;
          int bb = grow >> 12, ll = grow & (SL - 1);
          om[((size_t)(bb * NH + head) * SL + ll) * EHD + e] = acc[g][reg] + bv;
        }
      }
    } else if constexpr (EPI == 2) {
#pragma unroll
      for (int g = 0; g < NGW; ++g) {
        int col = ng * (NGW * 32) + g * 32 + (lane & 31);
        float bv = bias0[col];
#pragma unroll
        for (int reg = 0; reg < 16; ++reg) {
          int row_l = (reg & 3) + 8 * (reg >> 2) + hi4;
          int grow = row0 + mg * 32 + row_l;
          float a = acc[g][reg] + bv;
          out0[(size_t)grow * DFF + col] = 0.5f * a * (1.f + erff(a * 0.707106781186547524f));
        }
      }
    } else if constexpr (EPI == 3) {
#pragma unroll
      for (int g = 0; g < NGW; ++g) {
        int col = ng * (NGW * 32) + g * 32 + (lane & 31);
        float bv = bias0[col];
#pragma unroll
        for (int reg = 0; reg < 16; ++reg) {
          int row_l = (reg & 3) + 8 * (reg >> 2) + hi4;
          int grow = row0 + mg * 32 + row_l;
          int bb = grow >> 12, ll = grow & (SL - 1);
          out0[((size_t)(bb * NREP + col)) * SL + ll] = acc[g][reg] + bv;
        }
      }
    } else {  // EPI == 1: residual + LayerNorm -> h
      float bv[2], gwv[2], gbv[2];
#pragma unroll
      for (int g = 0; g < NGW; ++g) {
        int col = ng * (NGW * 32) + g * 32 + (lane & 31);
        bv[g] = bias0[col]; gwv[g] = gw[col]; gbv[g] = gb[col];
      }
      float ps[16], pq[16];
#pragma unroll
      for (int reg = 0; reg < 16; ++reg) {
        int row_l = (reg & 3) + 8 * (reg >> 2) + hi4;
        int grow = row0 + mg * 32 + row_l;
        float vsum = 0.f, qsum = 0.f;
#pragma unroll
        for (int g = 0; g < NGW; ++g) {
          int col = ng * (NGW * 32) + g * 32 + (lane & 31);
          float t = acc[g][reg] + bv[g] + hres[(size_t)grow * DM + col];
          acc[g][reg] = t;
          vsum += t; qsum += t * t;
        }
        vsum += __shfl_xor(vsum, 1, 32); qsum += __shfl_xor(qsum, 1, 32);
        vsum += __shfl_xor(vsum, 2, 32); qsum += __shfl_xor(qsum, 2, 32);
        vsum += __shfl_xor(vsum, 4, 32); qsum += __shfl_xor(qsum, 4, 32);
        vsum += __shfl_xor(vsum, 8, 32); qsum += __shfl_xor(qsum, 8, 32);
        vsum += __shfl_xor(vsum, 16, 32); qsum += __shfl_xor(qsum, 16, 32);
        ps[reg] = vsum; pq[reg] = qsum;
      }
      __syncthreads();
      if ((lane & 31) == 0) {
#pragma unroll
        for (int reg = 0; reg < 16; ++reg) {
          int row_l = (reg & 3) + 8 * (reg >> 2) + hi4;
          int rl = mg * 32 + row_l;
          red[rl * 4 + ng * 2 + 0] = ps[reg];
          red[rl * 4 + ng * 2 + 1] = pq[reg];
        }
      }
      __syncthreads();
#pragma unroll
      for (int reg = 0; reg < 16; ++reg) {
        int row_l = (reg & 3) + 8 * (reg >> 2) + hi4;
        int rl = mg * 32 + row_l;
        int grow = row0 + rl;
        float st = red[rl * 4 + 0] + red[rl * 4 + 2];
        float qt = red[rl * 4 + 1] + red[rl * 4 + 3];
        float mean = st * (1.f / 128.f);
        float var = qt * (1.f / 128.f) - mean * mean;
        float rstd = 1.0f / sqrtf(var + 1e-5f);
#pragma unroll
        for (int g = 0; g < NGW; ++g) {
          int col = ng * (NGW * 32) + g * 32 + (lane & 31);
          out0[(size_t)grow * DM + col] = (acc[g][reg] - mean) * rstd * gwv[g] + gbv[g];
        }
      }
    }
  }
#undef STAGE_B
#undef GEMM_PASS
}

// ---------------- sampled scores -> M (6-deep pipelined gathers) ----------------
__global__ __launch_bounds__(256) void sampM_kernel(const float* __restrict__ q,
    const float* __restrict__ k, const uint32_t* __restrict__ bitsT,
    float* __restrict__ M) {
  int tid = threadIdx.x;
  int bh = blockIdx.x & 63;          // bh%8 == blockIdx%8 -> XCD-local K
  int l = (blockIdx.x >> 6) * 256 + tid;
  const float* qr = q + ((size_t)bh * SL + l) * EHD;
  float4 q0 = *(const float4*)(qr + 0);
  float4 q1 = *(const float4*)(qr + 4);
  float4 q2 = *(const float4*)(qr + 8);
  float4 q3 = *(const float4*)(qr + 12);
  int ki[NC];
#pragma unroll
  for (int u = 0; u < NC; ++u) ki[u] = (int)(bitsT[u * SL + l] & (SL - 1));
  const float* kb = k + (size_t)bh * SL * EHD;
  float4 buf[6][4];
#define ISSUE(S, U) { const float* kr = kb + (size_t)ki[U] * EHD;                  \
    buf[S][0] = *(const float4*)(kr);     buf[S][1] = *(const float4*)(kr + 4);    \
    buf[S][2] = *(const float4*)(kr + 8); buf[S][3] = *(const float4*)(kr + 12); }
  ISSUE(0, 0) ISSUE(1, 1) ISSUE(2, 2) ISSUE(3, 3) ISSUE(4, 4) ISSUE(5, 5)
  float mx = -INFINITY, sm = 0.f;
#pragma unroll
  for (int u = 0; u < NC; ++u) {
    float4 k0 = buf[u % 6][0], k1 = buf[u % 6][1];
    float4 k2 = buf[u % 6][2], k3 = buf[u % 6][3];
    if (u + 6 < NC) { ISSUE(u % 6, u + 6) }
    float s = q0.x*k0.x + q0.y*k0.y + q0.z*k0.z + q0.w*k0.w
            + q1.x*k1.x + q1.y*k1.y + q1.z*k1.z + q1.w*k1.w
            + q2.x*k2.x + q2.y*k2.y + q2.z*k2.z + q2.w*k2.w
            + q3.x*k3.x + q3.y*k3.y + q3.z*k3.z + q3.w*k3.w;
    mx = fmaxf(mx, s);
    sm += s;
  }
#undef ISSUE
  M[(size_t)bh * SL + l] = mx - sm * (1.0f / (float)SL);
}

// ---------------- top-k (iterative argmax, wave butterfly, stable ties) ----------------
__global__ __launch_bounds__(256) void topk_kernel(const float* __restrict__ M,
                                                   int* __restrict__ top) {
  int bh  = blockIdx.x;
  int tid = threadIdx.x;
  int lane = tid & 63, wave = tid >> 6;
  __shared__ float vals[SL];
  __shared__ float wmax[4];
  __shared__ int   widx[4];
  for (int i = tid; i < SL; i += 256) vals[i] = M[(size_t)bh * SL + i];
  __syncthreads();
  for (int u = 0; u < NC; ++u) {
    float bm = -INFINITY; int bi = SL;
#pragma unroll
    for (int j = 0; j < SL / 256; ++j) {
      int i = tid + j * 256;
      float vv = vals[i];
      if (vv > bm) { bm = vv; bi = i; }
    }
#pragma unroll
    for (int off = 32; off > 0; off >>= 1) {
      float v2 = __shfl_xor(bm, off, 64);
      int   i2 = __shfl_xor(bi, off, 64);
      if (v2 > bm || (v2 == bm && i2 < bi)) { bm = v2; bi = i2; }
    }
    if (lane == 0) { wmax[wave] = bm; widx[wave] = bi; }
    __syncthreads();
    if (tid == 0) {
      float b0 = wmax[0]; int x0 = widx[0];
#pragma unroll
      for (int w = 1; w < 4; ++w) {
        float vw = wmax[w]; int iw = widx[w];
        if (vw > b0 || (vw == b0 && iw < x0)) { b0 = vw; x0 = iw; }
      }
      top[bh * NC + u] = x0;
      vals[x0] = -INFINITY;
    }
    __syncthreads();
  }
}

// ---------------- V mean over L ----------------
__global__ void vmean_kernel(const float* __restrict__ v, float* __restrict__ vmean) {
  int bh  = blockIdx.x;
  int tid = threadIdx.x;
  int e = tid & 15, g = tid >> 4;
  float s = 0.f;
  for (int l = g; l < SL; l += 16) s += v[((size_t)bh * SL + l) * EHD + e];
  __shared__ float red[256];
  red[tid] = s; __syncthreads();
  for (int st = 128; st >= 16; st >>= 1) {
    if (tid < st) red[tid] += red[tid + st];
    __syncthreads();
  }
  if (tid < EHD) vmean[bh * EHD + tid] = red[tid] * (1.0f / (float)SL);
}

// ---------------- ctx = broadcast vmean (float4) ----------------
__global__ void fillctx_kernel(const float* __restrict__ vmean, float* __restrict__ ctx) {
  int t = blockIdx.x * blockDim.x + threadIdx.x;
  if (t >= NBH * SL * 4) return;
  int e0 = (t & 3) * 4;
  int bh = t >> 14;
  *(float4*)(ctx + (size_t)t * 4) = *(const float4*)(vmean + bh * EHD + e0);
}

// ---------------- flash-style attention for top-27 queries ----------------
__global__ __launch_bounds__(256) void attn_flash(const float* __restrict__ q,
    const float* __restrict__ k, const float* __restrict__ v,
    const int* __restrict__ top, float* __restrict__ ctx) {
  int bh = blockIdx.x & 63, ug = blockIdx.x >> 6;
  int tid = threadIdx.x, wid = tid >> 6, lane = tid & 63;
  int base = ug * 7;
  int nq = (ug < 3) ? 7 : 6;
  bool has0 = (wid < nq);
  bool has1 = (wid + 4 < nq);
  int u0 = base + (has0 ? wid : 0);
  int u1 = base + (has1 ? wid + 4 : 0);
  int qi0 = top[bh * NC + u0];
  int qi1 = top[bh * NC + u1];
  float q0[16], q1[16];
  {
    const float* p0 = q + ((size_t)bh * SL + qi0) * EHD;
    const float* p1 = q + ((size_t)bh * SL + qi1) * EHD;
#pragma unroll
    for (int i = 0; i < 4; ++i) {
      float4 f = *(const float4*)(p0 + 4 * i);
      q0[4*i] = f.x; q0[4*i+1] = f.y; q0[4*i+2] = f.z; q0[4*i+3] = f.w;
      float4 g = *(const float4*)(p1 + 4 * i);
      q1[4*i] = g.x; q1[4*i+1] = g.y; q1[4*i+2] = g.z; q1[4*i+3] = g.w;
    }
  }
  float m0 = -INFINITY, m1 = -INFINITY, l0 = 0.f, l1 = 0.f;
  float a0[16], a1[16];
#pragma unroll
  for (int j = 0; j < 16; ++j) { a0[j] = 0.f; a1[j] = 0.f; }
  const float* kb = k + (size_t)bh * SL * EHD;
  const float* vb = v + (size_t)bh * SL * EHD;
  for (int t = 0; t < 64; ++t) {
    int ki = lane + (t << 6);
    float kr[16], vr[16];
    {
      const float* kp = kb + (size_t)ki * EHD;
      const float* vp = vb + (size_t)ki * EHD;
#pragma unroll
      for (int i = 0; i < 4; ++i) {
        float4 f = *(const float4*)(kp + 4 * i);
        kr[4*i] = f.x; kr[4*i+1] = f.y; kr[4*i+2] = f.z; kr[4*i+3] = f.w;
        float4 g = *(const float4*)(vp + 4 * i);
        vr[4*i] = g.x; vr[4*i+1] = g.y; vr[4*i+2] = g.z; vr[4*i+3] = g.w;
      }
    }
    float s0 = 0.f, s1 = 0.f;
#pragma unroll
    for (int j = 0; j < 16; ++j) { s0 += q0[j] * kr[j]; s1 += q1[j] * kr[j]; }
    s0 *= 0.25f; s1 *= 0.25f;
    {
      float d = s0 - m0;
      float e = expf(-fabsf(d));
      bool gt = d > 0.f;
      float c = gt ? e : 1.f;
      float p = gt ? 1.f : e;
      m0 = gt ? s0 : m0;
      l0 = l0 * c + p;
#pragma unroll
      for (int j = 0; j < 16; ++j) a0[j] = a0[j] * c + p * vr[j];
    }
    {
      float d = s1 - m1;
      float e = expf(-fabsf(d));
      bool gt = d > 0.f;
      float c = gt ? e : 1.f;
      float p = gt ? 1.f : e;
      m1 = gt ? s1 : m1;
      l1 = l1 * c + p;
#pragma unroll
      for (int j = 0; j < 16; ++j) a1[j] = a1[j] * c + p * vr[j];
    }
  }
  // butterfly merge across 64 lanes
#pragma unroll
  for (int off = 1; off < 64; off <<= 1) {
    {
      float mo = __shfl_xor(m0, off, 64);
      float lo_ = __shfl_xor(l0, off, 64);
      float mn = fmaxf(m0, mo);
      float cs = expf(m0 - mn), co = expf(mo - mn);
      l0 = l0 * cs + lo_ * co;
#pragma unroll
      for (int j = 0; j < 16; ++j) {
        float ao = __shfl_xor(a0[j], off, 64);
        a0[j] = a0[j] * cs + ao * co;
      }
      m0 = mn;
    }
    {
      float mo = __shfl_xor(m1, off, 64);
      float lo_ = __shfl_xor(l1, off, 64);
      float mn = fmaxf(m1, mo);
      float cs = expf(m1 - mn), co = expf(mo - mn);
      l1 = l1 * cs + lo_ * co;
#pragma unroll
      for (int j = 0; j < 16; ++j) {
        float ao = __shfl_xor(a1[j], off, 64);
        a1[j] = a1[j] * cs + ao * co;
      }
      m1 = mn;
    }
  }
  if (lane == 0 && has0) {
    float inv = 1.0f / l0;
    float* o = ctx + ((size_t)bh * SL + qi0) * EHD;
#pragma unroll
    for (int j = 0; j < 16; ++j) o[j] = a0[j] * inv;
  }
  if (lane == 0 && has1) {
    float inv = 1.0f / l1;
    float* o = ctx + ((size_t)bh * SL + qi1) * EHD;
#pragma unroll
    for (int j = 0; j < 16; ++j) o[j] = a1[j] * inv;
  }
}

// ---------------- launch ----------------
extern "C" void kernel_launch(void* const* d_in, const int* in_sizes, int n_in,
                              void* d_out, int out_size, void* d_ws, size_t ws_size,
                              hipStream_t stream) {
  const float* x   = (const float*)d_in[0];
  const float* Wq  = (const float*)d_in[1];
  const float* bq  = (const float*)d_in[2];
  const float* Wk  = (const float*)d_in[3];
  const float* bk  = (const float*)d_in[4];
  const float* Wv  = (const float*)d_in[5];
  const float* bv  = (const float*)d_in[6];
  const float* Wo  = (const float*)d_in[7];
  const float* bo  = (const float*)d_in[8];
  const float* W1  = (const float*)d_in[9];
  const float* b1  = (const float*)d_in[10];
  const float* W2  = (const float*)d_in[11];
  const float* b2  = (const float*)d_in[12];
  const float* ln1w = (const float*)d_in[13];
  const float* ln1b = (const float*)d_in[14];
  const float* ln2w = (const float*)d_in[15];
  const float* ln2b = (const float*)d_in[16];
  const float* lnfw = (const float*)d_in[17];
  const float* lnfb = (const float*)d_in[18];
  const float* Wp  = (const float*)d_in[19];
  const float* bp  = (const float*)d_in[20];
  float* out = (float*)d_out;

  float* ws = (float*)d_ws;
  float* h     = ws;                      // 4194304
  float* q     = ws + 4194304;            // 4194304
  float* k     = ws + 8388608;            // 4194304
  float* v     = ws + 12582912;           // 4194304
  float* ctx   = ws + 16777216;           // 4194304
  float* y     = ws + 20971520;           // 2097152
  float* M     = ws + 23068672;           // 262144
  float* vmean = ws + 23330816;           // 1024
  int*   top   = (int*)(ws + 23331840);   // 2048 float slots
  uint32_t* bitsT = (uint32_t*)(ws + 23333888); // 110592 slots
  f16* phi = (f16*)(ws + 23444480);       // 425984 f16
  f16* plo = (f16*)(ws + 23657472);       // 425984 f16

  transpose_x_kernel<<<dim3(SL / 32, DM / 32, NB), 256, 0, stream>>>(x, h);
  prep_weights<<<(PACK_TOTAL + 255) / 256, 256, 0, stream>>>(
      Wq, Wk, Wv, Wo, W1, W2, Wp, phi, plo);

  for (int l = 0; l < NLAY; ++l) {
    size_t lb = (size_t)l * 81920;
    gen_bits_kernel<<<(SL * NC + 255) / 256, 256, 0, stream>>>(bitsT, l);
    gemm_fused<4, 8, 0, 0><<<NROWS / 64, 256, 0, stream>>>(
        h, phi + lb, plo + lb, bq + l * DM, bk + l * DM, bv + l * DM,
        q, k, v, nullptr, nullptr, nullptr);
    sampM_kernel<<<NBH * SL / 256, 256, 0, stream>>>(q, k, bitsT, M);
    topk_kernel<<<NBH, 256, 0, stream>>>(M, top);
    vmean_kernel<<<NBH, 256, 0, stream>>>(v, vmean);
    fillctx_kernel<<<(NBH * SL * 4 + 255) / 256, 256, 0, stream>>>(vmean, ctx);
    attn_flash<<<256, 256, 0, stream>>>(q, k, v, top, ctx);
    gemm_fused<4, 8, 1, 1><<<NROWS / 64, 256, 0, stream>>>(
        ctx, phi + lb + 49152, plo + lb + 49152, bo + l * DM, nullptr, nullptr,
        h, nullptr, nullptr, ln1w + l * DM, ln1b + l * DM, h);
    gemm_fused<2, 8, 0, 2><<<NROWS / 64, 256, 0, stream>>>(
        h, phi + lb + 65536, plo + lb + 65536, b1 + l * DFF, nullptr, nullptr,
        y, nullptr, nullptr, nullptr, nullptr, nullptr);
    gemm_fused<4, 4, 0, 1><<<NROWS / 64, 256, 0, stream>>>(
        y, phi + lb + 73728, plo + lb + 73728, b2 + l * DM, nullptr, nullptr,
        h, nullptr, nullptr, ln2w + l * DM, ln2b + l * DM, h);
  }

  gemm_fused<4, 8, 3, 3><<<NROWS / 64, 256, 0, stream>>>(
      h, phi + 409600, plo + 409600, bp, nullptr, nullptr,
      out, nullptr, nullptr, lnfw, lnfb, nullptr);
}